// Round 6
// baseline (151.267 us; speedup 1.0000x reference)
//
#include <hip/hip_runtime.h>

#define PP 16384
#define SQH 0.70710678118654752440f  // sqrt(0.5)

typedef unsigned int u32;
typedef unsigned short u16;
typedef __attribute__((ext_vector_type(8))) short bfrag;    // 8 bf16
typedef __attribute__((ext_vector_type(4))) float ffrag;    // 16x16 C/D
typedef __attribute__((ext_vector_type(16))) float ffrag16; // 32x32 C/D
typedef __attribute__((ext_vector_type(4))) float f4;

union BU { bfrag v; uint4 u; };

__device__ __forceinline__ u32 pk2(float a, float b) {
  u32 ua = __float_as_uint(a), ub = __float_as_uint(b);
  return ((ua + 0x8000u) >> 16) | ((ub + 0x8000u) & 0xffff0000u);
}

// ---- workspace layout (bytes) ----
// [0, XTB_B)        xTb: (P+1, 8, 16) bf16  -- transposed in_pc, zero pad row
// [XTB_B, +18432)   WB : phase-2 conv-weight B-frags [2][9][64] uint4
// [+18432, +2048)   WR : residual B-frags [2][64] uint4
#define XTB_B ((size_t)(PP + 1) * 256)
#define WB_B  XTB_B
#define WR_B  (XTB_B + 18432)

// Blocks 0..255: LDS-transpose 64 points each (coalesced both sides).
// Blocks 256..260: WB/WR frag packing; block 256 also zeroes the pad row.
__global__ __launch_bounds__(256) void prep_kernel(
    const float* __restrict__ in_pc, const float* __restrict__ weights,
    const float* __restrict__ weight_res, u32* __restrict__ ws) {
  __shared__ u32 T[64 * 72];  // 64 points x 64 dwords, stride 72 (bank rotation)
  const int blk = blockIdx.x, t = threadIdx.x;
  if (blk < 256) {
    const int p0 = blk * 64;
    const int pl = t >> 2, i4 = t & 3;
#pragma unroll
    for (int b = 0; b < 8; ++b) {  // coalesced: consecutive t -> consecutive 16B
      f4 v = *(const f4*)(in_pc + ((size_t)b * PP + p0 + pl) * 16 + i4 * 4);
      T[pl * 72 + b * 8 + i4 * 2]     = pk2(v.x, v.y);
      T[pl * 72 + b * 8 + i4 * 2 + 1] = pk2(v.z, v.w);
    }
    __syncthreads();
#pragma unroll
    for (int k = 0; k < 4; ++k) {  // coalesced uint4 writes of xTb rows
      int idx = k * 256 + t;
      int pl2 = idx >> 4, c2 = (idx & 15) * 4;
      uint4 v = *(const uint4*)&T[pl2 * 72 + c2];
      *(uint4*)&ws[(size_t)(p0 + pl2) * 64 + c2] = v;
    }
    return;
  }
  if (blk == 256 && t < 32)  // zero pad row PP
    *(uint2*)&ws[(size_t)PP * 64 + t * 2] = make_uint2(0u, 0u);
  int e = (blk - 256) * 256 + t;
  if (e < 1152) {  // WB frag (nt, ks, l): B[k=ks*32+(l>>4)*8+j][n=nt*16+(l&15)]
    int nt = e / 576, rem = e - nt * 576;
    int ks = rem >> 6, l = rem & 63;
    int quad = l >> 4, n = l & 15;
    int k0 = ks * 32 + quad * 8;
    uint4 pkd = make_uint4(0u, 0u, 0u, 0u);
    if (k0 < 272) {
      int w = k0 >> 4, i0 = k0 & 15;
      const float* src = weights + w * 512 + (nt * 16 + n) * 16 + i0;
      f4 lo = *(const f4*)src;
      f4 hi = *(const f4*)(src + 4);
      pkd = make_uint4(pk2(lo.x, lo.y), pk2(lo.z, lo.w), pk2(hi.x, hi.y), pk2(hi.z, hi.w));
    }
    *(uint4*)((char*)ws + WB_B + (size_t)e * 16) = pkd;
  } else if (e < 1280) {  // WR frag
    int l2 = e - 1152, nt = l2 >> 6, l = l2 & 63;
    int quad = l >> 4, n = l & 15;
    uint4 pkd = make_uint4(0u, 0u, 0u, 0u);
    if (quad < 2) {
      const float* src = weight_res + (nt * 16 + n) * 16 + quad * 8;
      f4 lo = *(const f4*)src;
      f4 hi = *(const f4*)(src + 4);
      pkd = make_uint4(pk2(lo.x, lo.y), pk2(lo.z, lo.w), pk2(hi.x, hi.y), pk2(hi.z, hi.w));
    }
    *(uint4*)((char*)ws + WR_B + (size_t)(e - 1152) * 16) = pkd;
  }
}

// Main: 1024 blocks x 4 waves; FOUR points per wave, zero barriers.
// All nid s_loads + ww loads + gathers issued up front (MLP); then two
// pair-passes: phase1 (4x mfma_32x32x16 per point) -> A2 in LDS ->
// phase2 (9x2 mfma_16x16x32 + 2 residual MFMAs) -> ELU/mix epilogue.
__global__ __launch_bounds__(256, 4) void pconv_main(
    const u32* __restrict__ ws,
    const float* __restrict__ bias,      // (P, 32) f32
    const float* __restrict__ wwg,       // (P, 16, 17) f32
    const int*  __restrict__ nidg,       // (P, 16) i32
    float* __restrict__ out)             // (8, P, 32) f32
{
  __shared__ __attribute__((aligned(16))) u16 Abuf[4 * 16 * 296];  // 37888 B

  const u16*  __restrict__ xTb = (const u16*)ws;
  const uint4* __restrict__ WB = (const uint4*)((const char*)ws + WB_B);
  const uint4* __restrict__ WR = (const uint4*)((const char*)ws + WR_B);

  const int tid = threadIdx.x;
  const int wid = __builtin_amdgcn_readfirstlane(tid >> 6);
  const int lane = tid & 63;
  const int lo16 = lane & 15, quad = lane >> 4;   // 16x16 MFMA role
  const int col = lane & 31, h = lane >> 5;       // 32x32 MFMA role
  u16* __restrict__ Aw = Abuf + wid * (16 * 296);

  const int p0 = (blockIdx.x * 4 + wid) * 4;

  // ---- issue all independent loads up front ----
  int nid[4][16];
#pragma unroll
  for (int pt = 0; pt < 4; ++pt)
#pragma unroll
    for (int m = 0; m < 16; ++m) nid[pt][m] = nidg[(size_t)(p0 + pt) * 16 + m];

  BU bb[4];  // phase-1 ww B-frags, packed in-kernel
#pragma unroll
  for (int pt = 0; pt < 4; ++pt) {
    float v[8];
#pragma unroll
    for (int idx = 0; idx < 8; ++idx) {
      float x = 0.f;
      if (col < 17) x = wwg[(size_t)(p0 + pt) * 272 + (h * 8 + idx) * 17 + col];
      v[idx] = x;
    }
    bb[pt].u = make_uint4(pk2(v[0], v[1]), pk2(v[2], v[3]), pk2(v[4], v[5]), pk2(v[6], v[7]));
  }

  const int voffb = (col >> 4) * 16 + (col & 15);  // u16 units within a point row
  u32 ag[4][16];  // [pt][t*4+j] packed A dwords
#pragma unroll
  for (int pt = 0; pt < 4; ++pt)
#pragma unroll
    for (int j = 0; j < 4; ++j) {
      const u16* q0 = xTb + (size_t)nid[pt][h * 8 + 2 * j] * 128 + voffb;
      const u16* q1 = xTb + (size_t)nid[pt][h * 8 + 2 * j + 1] * 128 + voffb;
#pragma unroll
      for (int t = 0; t < 4; ++t)
        ag[pt][t * 4 + j] = (u32)q0[t * 32] | ((u32)q1[t * 32] << 16);
    }

  BU rb0, rb1;  // residual B-frags (stationary)
  rb0.u = WR[lane];
  rb1.u = WR[64 + lane];

#pragma unroll
  for (int pair = 0; pair < 2; ++pair) {
    const int pp0 = p0 + pair * 2;

    // zero K-tail [272,288) of all 16 A2 rows (epilogue scratch clobbers it)
    {
      int r = lane >> 2, c = lane & 3;
      *(uint2*)(Aw + r * 296 + 272 + c * 4) = make_uint2(0u, 0u);
    }

    // ---- phase 1: two points -> A2 ----
#pragma unroll
    for (int pt2 = 0; pt2 < 2; ++pt2) {
      const int pt = pair * 2 + pt2;
#pragma unroll
      for (int t = 0; t < 4; ++t) {
        BU aa;
        aa.u = make_uint4(ag[pt][t * 4 + 0], ag[pt][t * 4 + 1],
                          ag[pt][t * 4 + 2], ag[pt][t * 4 + 3]);
        ffrag16 c = {};
        c = __builtin_amdgcn_mfma_f32_32x32x16_bf16(aa.v, bb[pt].v, c, 0, 0, 0);
        if (col < 17) {
#pragma unroll
          for (int q = 0; q < 4; ++q) {
            int r = pt2 * 8 + 2 * t + (q >> 1);
            int i0 = 4 * h + 8 * (q & 1);
            u16* dst = Aw + r * 296 + col * 16 + i0;
            *(uint2*)dst = make_uint2(pk2(c[4 * q + 0], c[4 * q + 1]),
                                      pk2(c[4 * q + 2], c[4 * q + 3]));
          }
        }
      }
    }

    // ---- phase 2: C[16x32] = A2[16x288] * W ----
    ffrag acc0 = {0.f, 0.f, 0.f, 0.f}, acc1 = {0.f, 0.f, 0.f, 0.f};
#pragma unroll
    for (int ks = 0; ks < 9; ++ks) {
      bfrag af = *(const bfrag*)(Aw + lo16 * 296 + ks * 32 + quad * 8);
      BU b0, b1;
      b0.u = WB[ks * 64 + lane];
      b1.u = WB[576 + ks * 64 + lane];
      acc0 = __builtin_amdgcn_mfma_f32_16x16x32_bf16(af, b0.v, acc0, 0, 0, 0);
      acc1 = __builtin_amdgcn_mfma_f32_16x16x32_bf16(af, b1.v, acc1, 0, 0, 0);
    }
    // residual from bf16 xTb self rows
    const int p_r = pp0 + (lo16 >> 3), b_r = lo16 & 7;
    BU su;
    su.u = make_uint4(0u, 0u, 0u, 0u);
    if (quad < 2)
      su.u = *(const uint4*)(xTb + (size_t)p_r * 128 + b_r * 16 + quad * 8);
    ffrag rz = {0.f, 0.f, 0.f, 0.f};
    ffrag res0 = __builtin_amdgcn_mfma_f32_16x16x32_bf16(su.v, rb0.v, rz, 0, 0, 0);
    ffrag res1 = __builtin_amdgcn_mfma_f32_16x16x32_bf16(su.v, rb1.v, rz, 0, 0, 0);

    // ---- epilogue: bias/ELU/mix -> LDS f32 [16][40] -> full-line stores ----
    float* Ef = (float*)Aw;
#pragma unroll
    for (int j = 0; j < 4; ++j) {
      int r = quad * 4 + j;
      int p_e = pp0 + (r >> 3);
      float c0 = acc0[j] + bias[(size_t)p_e * 32 + lo16];
      float c1 = acc1[j] + bias[(size_t)p_e * 32 + 16 + lo16];
      float e0 = c0 > 0.f ? c0 : (__expf(c0) - 1.f);
      float e1 = c1 > 0.f ? c1 : (__expf(c1) - 1.f);
      Ef[r * 40 + lo16]      = SQH * e0 + SQH * res0[j];
      Ef[r * 40 + 16 + lo16] = SQH * e1 + SQH * res1[j];
    }
#pragma unroll
    for (int k = 0; k < 2; ++k) {
      int rr = (lane >> 3) + 8 * k;
      int cc = lane & 7;
      f4 v = *(const f4*)(Ef + rr * 40 + cc * 4);
      int p_s = pp0 + (rr >> 3), b_s = rr & 7;
      *(f4*)(out + ((size_t)b_s * PP + p_s) * 32 + cc * 4) = v;
    }
  }
}

extern "C" void kernel_launch(void* const* d_in, const int* in_sizes, int n_in,
                              void* d_out, int out_size, void* d_ws, size_t ws_size,
                              hipStream_t stream) {
  const float* in_pc       = (const float*)d_in[0];
  const float* weights     = (const float*)d_in[1];
  const float* bias        = (const float*)d_in[2];
  const float* w_weights   = (const float*)d_in[3];
  const float* weight_res  = (const float*)d_in[4];
  const int*   neighbor_id = (const int*)d_in[5];
  float* out = (float*)d_out;
  u32* ws = (u32*)d_ws;  // needs ~4.3 MB

  hipLaunchKernelGGL(prep_kernel, dim3(261), dim3(256), 0, stream,
                     in_pc, weights, weight_res, ws);
  // 1024 blocks x 4 waves x 4 points = 16384 points
  hipLaunchKernelGGL(pconv_main, dim3(1024), dim3(256), 0, stream,
                     ws, bias, w_weights, neighbor_id, out);
}

// Round 7
// 103.777 us; speedup vs baseline: 1.4576x; 1.4576x over previous
//
#include <hip/hip_runtime.h>

#define PP 16384
#define SQH 0.70710678118654752440f  // sqrt(0.5)

typedef unsigned int u32;
typedef unsigned short u16;
typedef __attribute__((ext_vector_type(8))) short bfrag;    // 8 bf16
typedef __attribute__((ext_vector_type(4))) float ffrag;    // 16x16 C/D
typedef __attribute__((ext_vector_type(16))) float ffrag16; // 32x32 C/D
typedef __attribute__((ext_vector_type(4))) float f4;

union BU { bfrag v; uint4 u; };

__device__ __forceinline__ u32 pk2(float a, float b) {
  u32 ua = __float_as_uint(a), ub = __float_as_uint(b);
  return ((ua + 0x8000u) >> 16) | ((ub + 0x8000u) & 0xffff0000u);
}

// ---- workspace layout (bytes) ----
// [0, XTB_B)        xTb: (P+1, 8, 16) bf16  -- transposed in_pc, zero pad row
// [XTB_B, +18432)   WB : phase-2 conv-weight B-frags [2][9][64] uint4
// [+18432, +2048)   WR : residual B-frags [2][64] uint4
#define XTB_B ((size_t)(PP + 1) * 256)
#define WB_B  XTB_B
#define WR_B  (XTB_B + 18432)

// Blocks 0..255: LDS-transpose 64 points each (coalesced both sides).
// Blocks 256..260: WB/WR frag packing; block 256 also zeroes the pad row.
__global__ __launch_bounds__(256) void prep_kernel(
    const float* __restrict__ in_pc, const float* __restrict__ weights,
    const float* __restrict__ weight_res, u32* __restrict__ ws) {
  __shared__ u32 T[64 * 72];  // 64 points x 64 dwords, stride 72 (bank rotation)
  const int blk = blockIdx.x, t = threadIdx.x;
  if (blk < 256) {
    const int p0 = blk * 64;
    const int pl = t >> 2, i4 = t & 3;
#pragma unroll
    for (int b = 0; b < 8; ++b) {  // coalesced: consecutive t -> consecutive 16B
      f4 v = *(const f4*)(in_pc + ((size_t)b * PP + p0 + pl) * 16 + i4 * 4);
      T[pl * 72 + b * 8 + i4 * 2]     = pk2(v.x, v.y);
      T[pl * 72 + b * 8 + i4 * 2 + 1] = pk2(v.z, v.w);
    }
    __syncthreads();
#pragma unroll
    for (int k = 0; k < 4; ++k) {  // coalesced uint4 writes of xTb rows
      int idx = k * 256 + t;
      int pl2 = idx >> 4, c2 = (idx & 15) * 4;
      uint4 v = *(const uint4*)&T[pl2 * 72 + c2];
      *(uint4*)&ws[(size_t)(p0 + pl2) * 64 + c2] = v;
    }
    return;
  }
  if (blk == 256 && t < 32)  // zero pad row PP
    *(uint2*)&ws[(size_t)PP * 64 + t * 2] = make_uint2(0u, 0u);
  int e = (blk - 256) * 256 + t;
  if (e < 1152) {  // WB frag (nt, ks, l): B[k=ks*32+(l>>4)*8+j][n=nt*16+(l&15)]
    int nt = e / 576, rem = e - nt * 576;
    int ks = rem >> 6, l = rem & 63;
    int quad = l >> 4, n = l & 15;
    int k0 = ks * 32 + quad * 8;
    uint4 pkd = make_uint4(0u, 0u, 0u, 0u);
    if (k0 < 272) {
      int w = k0 >> 4, i0 = k0 & 15;
      const float* src = weights + w * 512 + (nt * 16 + n) * 16 + i0;
      f4 lo = *(const f4*)src;
      f4 hi = *(const f4*)(src + 4);
      pkd = make_uint4(pk2(lo.x, lo.y), pk2(lo.z, lo.w), pk2(hi.x, hi.y), pk2(hi.z, hi.w));
    }
    *(uint4*)((char*)ws + WB_B + (size_t)e * 16) = pkd;
  } else if (e < 1280) {  // WR frag
    int l2 = e - 1152, nt = l2 >> 6, l = l2 & 63;
    int quad = l >> 4, n = l & 15;
    uint4 pkd = make_uint4(0u, 0u, 0u, 0u);
    if (quad < 2) {
      const float* src = weight_res + (nt * 16 + n) * 16 + quad * 8;
      f4 lo = *(const f4*)src;
      f4 hi = *(const f4*)(src + 4);
      pkd = make_uint4(pk2(lo.x, lo.y), pk2(lo.z, lo.w), pk2(hi.x, hi.y), pk2(hi.z, hi.w));
    }
    *(uint4*)((char*)ws + WR_B + (size_t)(e - 1152) * 16) = pkd;
  }
}

// Main: 2048 blocks x 4 waves; ONE point-pair per wave (r5 structure — 4-pt
// variant spilled: 64-VGPR ag[] forced 135 MB of scratch traffic in r6).
// ww B-frags packed in-kernel (no WW1 table). Zero barriers.
__global__ __launch_bounds__(256, 4) void pconv_main(
    const u32* __restrict__ ws,
    const float* __restrict__ bias,      // (P, 32) f32
    const float* __restrict__ wwg,       // (P, 16, 17) f32
    const int*  __restrict__ nidg,       // (P, 16) i32
    float* __restrict__ out)             // (8, P, 32) f32
{
  __shared__ __attribute__((aligned(16))) u16 Abuf[4 * 16 * 296];  // 37888 B

  const u16*  __restrict__ xTb = (const u16*)ws;
  const uint4* __restrict__ WB = (const uint4*)((const char*)ws + WB_B);
  const uint4* __restrict__ WR = (const uint4*)((const char*)ws + WR_B);

  const int tid = threadIdx.x;
  const int wid = __builtin_amdgcn_readfirstlane(tid >> 6);
  const int lane = tid & 63;
  const int lo16 = lane & 15, quad = lane >> 4;   // 16x16 MFMA role
  const int col = lane & 31, h = lane >> 5;       // 32x32 MFMA role
  u16* __restrict__ Aw = Abuf + wid * (16 * 296);

  const int p0 = (blockIdx.x * 4 + wid) * 2;

  // zero K-tail [272,288) of all 16 A2 rows
  {
    int r = lane >> 2, c = lane & 3;
    *(uint2*)(Aw + r * 296 + 272 + c * 4) = make_uint2(0u, 0u);
  }

  // ---- issue all independent loads up front ----
  int nid0[16], nid1[16];
#pragma unroll
  for (int m = 0; m < 16; ++m) nid0[m] = nidg[(size_t)p0 * 16 + m];       // s_loads
#pragma unroll
  for (int m = 0; m < 16; ++m) nid1[m] = nidg[(size_t)(p0 + 1) * 16 + m];

  BU bb0, bb1;  // phase-1 ww B-frags packed in-kernel
  {
    float v0[8], v1[8];
#pragma unroll
    for (int idx = 0; idx < 8; ++idx) {
      float x0 = 0.f, x1 = 0.f;
      if (col < 17) {
        x0 = wwg[(size_t)p0 * 272 + (h * 8 + idx) * 17 + col];
        x1 = wwg[(size_t)(p0 + 1) * 272 + (h * 8 + idx) * 17 + col];
      }
      v0[idx] = x0; v1[idx] = x1;
    }
    bb0.u = make_uint4(pk2(v0[0], v0[1]), pk2(v0[2], v0[3]), pk2(v0[4], v0[5]), pk2(v0[6], v0[7]));
    bb1.u = make_uint4(pk2(v1[0], v1[1]), pk2(v1[2], v1[3]), pk2(v1[4], v1[5]), pk2(v1[6], v1[7]));
  }

  const int voffb = (col >> 4) * 16 + (col & 15);  // u16 units within a point row
  u32 a0[4][4], a1[4][4];  // packed A dwords, 32 VGPRs total
#pragma unroll
  for (int j = 0; j < 4; ++j) {
    const u16* q0 = xTb + (size_t)nid0[h * 8 + 2 * j] * 128 + voffb;
    const u16* q1 = xTb + (size_t)nid0[h * 8 + 2 * j + 1] * 128 + voffb;
#pragma unroll
    for (int t = 0; t < 4; ++t)
      a0[t][j] = (u32)q0[t * 32] | ((u32)q1[t * 32] << 16);
  }
#pragma unroll
  for (int j = 0; j < 4; ++j) {
    const u16* q0 = xTb + (size_t)nid1[h * 8 + 2 * j] * 128 + voffb;
    const u16* q1 = xTb + (size_t)nid1[h * 8 + 2 * j + 1] * 128 + voffb;
#pragma unroll
    for (int t = 0; t < 4; ++t)
      a1[t][j] = (u32)q0[t * 32] | ((u32)q1[t * 32] << 16);
  }

  // hoist bias + residual self rows + residual B-frags (off the tail)
  float blo[4], bhi[4];
#pragma unroll
  for (int j = 0; j < 4; ++j) {
    int p_e = p0 + ((quad * 4 + j) >> 3);
    blo[j] = bias[(size_t)p_e * 32 + lo16];
    bhi[j] = bias[(size_t)p_e * 32 + 16 + lo16];
  }
  BU su;
  su.u = make_uint4(0u, 0u, 0u, 0u);
  {
    const int p_r = p0 + (lo16 >> 3), b_r = lo16 & 7;
    if (quad < 2)
      su.u = *(const uint4*)(xTb + (size_t)p_r * 128 + b_r * 16 + quad * 8);
  }
  BU rb0, rb1;
  rb0.u = WR[lane];
  rb1.u = WR[64 + lane];

  // ---- phase 1: two points -> A2 in LDS ----
#pragma unroll
  for (int pt = 0; pt < 2; ++pt) {
    const u32 (&ad)[4][4] = pt ? a1 : a0;
    BU bb = pt ? bb1 : bb0;
#pragma unroll
    for (int t = 0; t < 4; ++t) {
      BU aa;
      aa.u = make_uint4(ad[t][0], ad[t][1], ad[t][2], ad[t][3]);
      ffrag16 c = {};
      c = __builtin_amdgcn_mfma_f32_32x32x16_bf16(aa.v, bb.v, c, 0, 0, 0);
      if (col < 17) {
#pragma unroll
        for (int q = 0; q < 4; ++q) {
          int r = pt * 8 + 2 * t + (q >> 1);
          int i0 = 4 * h + 8 * (q & 1);
          u16* dst = Aw + r * 296 + col * 16 + i0;
          *(uint2*)dst = make_uint2(pk2(c[4 * q + 0], c[4 * q + 1]),
                                    pk2(c[4 * q + 2], c[4 * q + 3]));
        }
      }
    }
  }

  // ---- phase 2: C[16x32] = A2[16x288] * W ----
  ffrag acc0 = {0.f, 0.f, 0.f, 0.f}, acc1 = {0.f, 0.f, 0.f, 0.f};
#pragma unroll
  for (int ks = 0; ks < 9; ++ks) {
    bfrag af = *(const bfrag*)(Aw + lo16 * 296 + ks * 32 + quad * 8);
    BU b0, b1;
    b0.u = WB[ks * 64 + lane];
    b1.u = WB[576 + ks * 64 + lane];
    acc0 = __builtin_amdgcn_mfma_f32_16x16x32_bf16(af, b0.v, acc0, 0, 0, 0);
    acc1 = __builtin_amdgcn_mfma_f32_16x16x32_bf16(af, b1.v, acc1, 0, 0, 0);
  }
  ffrag rz = {0.f, 0.f, 0.f, 0.f};
  ffrag res0 = __builtin_amdgcn_mfma_f32_16x16x32_bf16(su.v, rb0.v, rz, 0, 0, 0);
  ffrag res1 = __builtin_amdgcn_mfma_f32_16x16x32_bf16(su.v, rb1.v, rz, 0, 0, 0);

  // ---- epilogue: bias/ELU/mix -> LDS f32 [16][40] -> full-line stores ----
  float* Ef = (float*)Aw;
#pragma unroll
  for (int j = 0; j < 4; ++j) {
    int r = quad * 4 + j;
    float c0 = acc0[j] + blo[j];
    float c1 = acc1[j] + bhi[j];
    float e0 = c0 > 0.f ? c0 : (__expf(c0) - 1.f);
    float e1 = c1 > 0.f ? c1 : (__expf(c1) - 1.f);
    Ef[r * 40 + lo16]      = SQH * e0 + SQH * res0[j];
    Ef[r * 40 + 16 + lo16] = SQH * e1 + SQH * res1[j];
  }
#pragma unroll
  for (int k = 0; k < 2; ++k) {
    int rr = (lane >> 3) + 8 * k;
    int cc = lane & 7;
    f4 v = *(const f4*)(Ef + rr * 40 + cc * 4);
    int p_s = p0 + (rr >> 3), b_s = rr & 7;
    *(f4*)(out + ((size_t)b_s * PP + p_s) * 32 + cc * 4) = v;
  }
}

extern "C" void kernel_launch(void* const* d_in, const int* in_sizes, int n_in,
                              void* d_out, int out_size, void* d_ws, size_t ws_size,
                              hipStream_t stream) {
  const float* in_pc       = (const float*)d_in[0];
  const float* weights     = (const float*)d_in[1];
  const float* bias        = (const float*)d_in[2];
  const float* w_weights   = (const float*)d_in[3];
  const float* weight_res  = (const float*)d_in[4];
  const int*   neighbor_id = (const int*)d_in[5];
  float* out = (float*)d_out;
  u32* ws = (u32*)d_ws;  // needs ~4.3 MB

  hipLaunchKernelGGL(prep_kernel, dim3(261), dim3(256), 0, stream,
                     in_pc, weights, weight_res, ws);
  // 2048 blocks x 4 waves x 2 points = 16384 points
  hipLaunchKernelGGL(pconv_main, dim3(2048), dim3(256), 0, stream,
                     ws, bias, w_weights, neighbor_id, out);
}